// Round 4
// baseline (231.713 us; speedup 1.0000x reference)
//
#include <hip/hip_runtime.h>

#define G_VOX  68921      // 41^3
#define GMAX   68920      // last valid element index
#define NSEG   272        // 272 segments of 256 elements (phase-shifted); last few are padding
#define SEG_PER_PART 68   // NSEG / 4 partitions per nc in the split-scan kernel
#define MWORDS 2176       // 32-bit sphere-mask words (69632 bits)
#define NEGV (-1.0e9f)
#define VTH  (-1.0e8f)

#define WS_TAB_OFF 16384                          // byte offset of (val,idx) table in workspace
#define WS_NEEDED  (WS_TAB_OFF + 512 * NSEG * 4 * 2)   // mask area + 512x272 floats + ints

__device__ __forceinline__ bool sphere_bit(const float* __restrict__ gxyz, int e) {
    if (e >= G_VOX) return false;
    float gx = gxyz[e * 3 + 0];
    float gy = gxyz[e * 3 + 1];
    float gz = gxyz[e * 3 + 2];
    float s  = __fadd_rn(__fadd_rn(__fmul_rn(gx, gx), __fmul_rn(gy, gy)),
                         __fmul_rn(gz, gz));
    return (__fsqrt_rn(s) <= 6.0f);   // bit-matches np.linalg.norm(grid_xyz) <= 6
}

// ---------------- Kernel 0: sphere word-mask ----------------
__global__ __launch_bounds__(256) void build_mask(
    const float* __restrict__ gxyz, unsigned int* __restrict__ mask)
{
    int idx = blockIdx.x * 256 + threadIdx.x;    // 0..69631
    unsigned long long bal = __ballot(sphere_bit(gxyz, idx));
    int lane = threadIdx.x & 63;
    if (lane == 0)       mask[idx >> 5] = (unsigned int)bal;
    else if (lane == 32) mask[idx >> 5] = (unsigned int)(bal >> 32);
}

// 8-lane segment scan core: lanes l8=0..7 cooperatively scan one 256-element segment.
// smw points at the mask word for this segment's first quad (global word 8*s).
// 8 independent UNCONDITIONAL float4 loads (tail clamped to an aligned in-bounds quad;
// mask bits beyond the last valid element are 0, so clamped garbage is never selected).
// Two-word 64-bit mask extract (field straddles a word when sh>28 — the R1 bug).
// 3-level xor-shuffle reduce; all 8 lanes return the group winner.
__device__ __forceinline__ void seg_scan8_core(
    const float* __restrict__ dens, const unsigned int* smw,
    int ebase, int sh, int eclamp, float& bv, int& bi)
{
    bv = NEGV; bi = ebase;
    float4       dq[8];
    unsigned int bq[8];
    unsigned int wprev = smw[0];
    #pragma unroll
    for (int q = 0; q < 8; ++q) {
        const int e = ebase + 32 * q;
        const unsigned int wnext = smw[q + 1];
        unsigned long long mw = ((unsigned long long)wnext << 32) | wprev;
        bq[q] = (unsigned int)(mw >> sh) & 0xFu;
        wprev = wnext;
        const int ec = (e + 3 <= GMAX) ? e : eclamp;       // branchless tail clamp
        dq[q] = *reinterpret_cast<const float4*>(dens + ec);
    }
    #pragma unroll
    for (int q = 0; q < 8; ++q) {
        const int e = ebase + 32 * q;
        float v0 = (bq[q] & 1u) ? dq[q].x : NEGV;
        float v1 = (bq[q] & 2u) ? dq[q].y : NEGV;
        float v2 = (bq[q] & 4u) ? dq[q].z : NEGV;
        float v3 = (bq[q] & 8u) ? dq[q].w : NEGV;
        if (v0 > bv) { bv = v0; bi = e;     }   // ascending e + strict > = first occurrence
        if (v1 > bv) { bv = v1; bi = e + 1; }
        if (v2 > bv) { bv = v2; bi = e + 2; }
        if (v3 > bv) { bv = v3; bi = e + 3; }
    }
    #pragma unroll
    for (int off = 4; off > 0; off >>= 1) {     // 3-level reduce within 8-lane group
        float ov = __shfl_xor(bv, off);
        int   oi = __shfl_xor(bi, off);
        if (ov > bv || (ov == bv && oi < bi)) { bv = ov; bi = oi; }
    }
}

// ---------------- Kernel A: pure-streaming segment-argmax table ----------------
// 2048 blocks x 256 threads: block (nc, part) scans segments [part*68, part*68+68)
// of channel nc (a contiguous 68KB density slice) and writes per-segment (val,idx).
// No barriers after the 2.2KB mask stage-in -> full-rate streaming at 8 blocks/CU.
__global__ __launch_bounds__(256) void scan_table(
    const float* __restrict__ density,
    const unsigned int* __restrict__ maskg,
    float* __restrict__ wval, int* __restrict__ widx)
{
    __shared__ unsigned int lm[SEG_PER_PART * 8 + 2];    // words [8*s0, 8*s0+545)
    const int bid  = blockIdx.x;
    const int nc   = bid >> 2;
    const int part = bid & 3;
    const int s0   = part * SEG_PER_PART;
    const int h    = (-nc) & 3;                  // phase: nc*68921 + h == 0 (mod 4)
    const int tid  = threadIdx.x;
    const int lane = tid & 63;
    const int w    = tid >> 6;                   // wave 0..3
    const int s8   = lane >> 3;
    const int l8   = lane & 7;
    const float* dens = density + (size_t)nc * G_VOX;
    const int eclamp = h + ((GMAX - 3 - h) & ~3);
    const int wbase  = 8 * s0;

    for (int i = tid; i < SEG_PER_PART * 8 + 2; i += 256) {
        const int gw = wbase + i;
        lm[i] = (gw < MWORDS) ? maskg[gw] : 0u;  // word 2176 (last block) is padding -> 0
    }
    __syncthreads();

    const int sh = h + 4 * l8;                   // <= 31 always
    #pragma unroll
    for (int j = 0; j < 3; ++j) {
        const int sl = j * 32 + w * 8 + s8;      // 0..95; active < 68
        if (sl < SEG_PER_PART) {                 // group-uniform branch
            const int s = s0 + sl;
            const int ebase = h + 256 * s + 4 * l8;
            float bv; int bi;
            seg_scan8_core(dens, lm + 8 * sl, ebase, sh, eclamp, bv, bi);
            if (l8 == 0) { wval[nc * NSEG + s] = bv; widx[nc * NSEG + s] = bi; }
        }
    }
}

// ---------------- Kernel B: K=4 pick / NMS / recompute + epilogue, one block per nc ----------------
__global__ __launch_bounds__(512) void nms_peaks(
    const float* __restrict__ density,
    const float* __restrict__ gxyz,
    const unsigned int* __restrict__ maskg,
    const float* __restrict__ wval, const int* __restrict__ widx,
    const float* __restrict__ Rm, const float* __restrict__ tp,
    const float* __restrict__ nmask,
    float* __restrict__ out)
{
    __shared__ unsigned int smask[MWORDS + 2];   // +2: suppression's 64-bit clears touch wd+1
    __shared__ float sval[NSEG];
    __shared__ int   sidx[NSEG];
    __shared__ int   flag[NSEG];
    __shared__ int   list[104];
    __shared__ int   nlist;
    __shared__ float rv[8];
    __shared__ int   ri[8];
    __shared__ float pval[4];
    __shared__ int   pidx[4];
    __shared__ int   pki[4], pkj[4], pkk[4];

    const int tid  = threadIdx.x;
    const int nc   = blockIdx.x;                 // 0..511
    const int n    = nc >> 2;
    const int h    = (-nc) & 3;
    const int lane = tid & 63;
    const int w    = tid >> 6;                   // wave 0..7
    const int s8   = lane >> 3;
    const int l8   = lane & 7;
    const float* dens = density + (size_t)nc * G_VOX;
    const int eclamp = h + ((GMAX - 3 - h) & ~3);

    for (int i = tid; i < MWORDS + 2; i += 512) smask[i] = (i < MWORDS) ? maskg[i] : 0u;
    for (int i = tid; i < NSEG; i += 512) {
        flag[i] = 0;
        sval[i] = wval[nc * NSEG + i];
        sidx[i] = widx[nc * NSEG + i];
    }
    __syncthreads();

    for (int p = 0; p < 4; ++p) {
        float bv = -INFINITY;
        int   bi = 0x7FFFFFFF;
        if (tid < NSEG) { bv = sval[tid]; bi = sidx[tid]; }
        #pragma unroll
        for (int off = 32; off > 0; off >>= 1) {
            float ov = __shfl_down(bv, off);
            int   oi = __shfl_down(bi, off);
            if (ov > bv || (ov == bv && oi < bi)) { bv = ov; bi = oi; }
        }
        if (lane == 0) { rv[w] = bv; ri[w] = bi; }
        __syncthreads();
        if (w == 0) {
            bv = (lane < 8) ? rv[lane] : -INFINITY;
            bi = (lane < 8) ? ri[lane] : 0x7FFFFFFF;
            #pragma unroll
            for (int off = 4; off > 0; off >>= 1) {
                float ov = __shfl_down(bv, off);
                int   oi = __shfl_down(bi, off);
                if (ov > bv || (ov == bv && oi < bi)) { bv = ov; bi = oi; }
            }
            if (lane == 0) {
                pval[p] = bv;
                pidx[p] = bi;
                int pi = bi / 1681;
                int rr = bi - pi * 1681;
                int pj = rr / 41;
                pki[p] = pi; pkj[p] = pj; pkk[p] = rr - pj * 41;
                nlist = 0;
            }
        }
        __syncthreads();

        if (p < 3 && pval[p] > VTH) {
            // clear 7x7x7 Chebyshev cube bits in LDS mask; collect affected segments
            if (tid < 49) {
                int di = tid / 7 - 3, dj = tid % 7 - 3;
                int ii = pki[p] + di, jj = pkj[p] + dj;
                if (ii >= 0 && ii <= 40 && jj >= 0 && jj <= 40) {
                    int k0 = pkk[p] - 3; if (k0 < 0)  k0 = 0;
                    int k1 = pkk[p] + 3; if (k1 > 40) k1 = 40;
                    int b0  = ii * 1681 + jj * 41 + k0;
                    int cnt = k1 - k0 + 1;
                    unsigned long long m = ((1ull << cnt) - 1ull) << (b0 & 31);
                    int w0 = b0 >> 5;
                    atomicAnd(&smask[w0], ~(unsigned int)m);
                    unsigned int hi = (unsigned int)(m >> 32);
                    if (hi) atomicAnd(&smask[w0 + 1], ~hi);
                    // phase-shifted segment ids containing this run
                    int s0 = (b0 > h) ? (b0 - h) >> 8 : 0;
                    int s1 = (b0 + cnt - 1 > h) ? (b0 + cnt - 1 - h) >> 8 : 0;
                    if (atomicMax(&flag[s0], p + 1) < p + 1) {
                        int q = atomicAdd(&nlist, 1); list[q] = s0;
                    }
                    if (s1 != s0 && atomicMax(&flag[s1], p + 1) < p + 1) {
                        int q = atomicAdd(&nlist, 1); list[q] = s1;
                    }
                }
            }
            __syncthreads();
            // recompute flagged segments: one 8-lane group per list entry (64 segs/sweep)
            const int cnt = nlist;
            for (int base = 0; base < cnt; base += 64) {
                const int slot = base + w * 8 + s8;
                if (slot < cnt) {                // uniform within the 8-lane group
                    const int s = list[slot];
                    const int ebase = h + 256 * s + 4 * l8;
                    float bv2; int bi2;
                    seg_scan8_core(dens, smask + 8 * s, ebase, h + 4 * l8, eclamp, bv2, bi2);
                    if (l8 == 0) { sval[s] = bv2; sidx[s] = bi2; }
                }
            }
        }
        __syncthreads();
    }

    // ---- epilogue: one peak per thread ----
    if (tid < 4) {
        const int k   = tid;
        const float val = pval[k];
        const int   idx = pidx[k];
        const bool valid = val > VTH;
        float gx = 0.0f, gy = 0.0f, gz = 0.0f;
        if (valid) {
            gx = gxyz[idx * 3 + 0];
            gy = gxyz[idx * 3 + 1];
            gz = gxyz[idx * 3 + 2];
        }
        const float nm = nmask[n];
        const float* R = Rm + n * 9;
        const float* t = tp + n * 3;
        float wx = R[0] * gx + R[1] * gy + R[2] * gz + t[0];
        float wy = R[3] * gx + R[4] * gy + R[5] * gz + t[1];
        float wz = R[6] * gx + R[7] * gy + R[8] * gz + t[2];

        const size_t o3 = ((size_t)nc * 4 + k) * 3;
        out[o3 + 0] = gx * nm;                       // coords_local [1,128,4,4,3]
        out[o3 + 1] = gy * nm;
        out[o3 + 2] = gz * nm;
        out[6144 + o3 + 0] = wx * nm;                // coords_global
        out[6144 + o3 + 1] = wy * nm;
        out[6144 + o3 + 2] = wz * nm;
        const size_t o1 = (size_t)nc * 4 + k;
        out[12288 + o1] = (valid ? val : NEGV) * nm; // scores
        out[14336 + o1] = (valid && nm != 0.0f) ? 1.0f : 0.0f;  // mask
    }
}

// ---------------- Fallback: single fused kernel (proven-correct path) ----------------
__global__ __launch_bounds__(512) void fused_peaks(
    const float* __restrict__ density,
    const float* __restrict__ gxyz,
    const unsigned int* __restrict__ maskg,
    const float* __restrict__ Rm, const float* __restrict__ tp,
    const float* __restrict__ nmask,
    float* __restrict__ out)
{
    __shared__ unsigned int smask[MWORDS + 2];
    __shared__ float sval[NSEG];
    __shared__ int   sidx[NSEG];
    __shared__ int   flag[NSEG];
    __shared__ int   list[104];
    __shared__ int   nlist;
    __shared__ float rv[8];
    __shared__ int   ri[8];
    __shared__ float pval[4];
    __shared__ int   pidx[4];
    __shared__ int   pki[4], pkj[4], pkk[4];

    const int tid  = threadIdx.x;
    const int nc   = blockIdx.x;
    const int n    = nc >> 2;
    const int h    = (-nc) & 3;
    const int lane = tid & 63;
    const int w    = tid >> 6;
    const int s8   = lane >> 3;
    const int l8   = lane & 7;
    const float* dens = density + (size_t)nc * G_VOX;
    const int eclamp = h + ((GMAX - 3 - h) & ~3);

    for (int i = tid; i < MWORDS + 2; i += 512) smask[i] = (i < MWORDS) ? maskg[i] : 0u;
    for (int i = tid; i < NSEG; i += 512) flag[i] = 0;
    __syncthreads();

    for (int g = w; g < 34; g += 8) {
        const int s = g * 8 + s8;
        const int ebase = h + 256 * s + 4 * l8;
        float bv; int bi;
        seg_scan8_core(dens, smask + 8 * s, ebase, h + 4 * l8, eclamp, bv, bi);
        if (l8 == 0) { sval[s] = bv; sidx[s] = bi; }
    }
    __syncthreads();

    for (int p = 0; p < 4; ++p) {
        float bv = -INFINITY;
        int   bi = 0x7FFFFFFF;
        if (tid < NSEG) { bv = sval[tid]; bi = sidx[tid]; }
        #pragma unroll
        for (int off = 32; off > 0; off >>= 1) {
            float ov = __shfl_down(bv, off);
            int   oi = __shfl_down(bi, off);
            if (ov > bv || (ov == bv && oi < bi)) { bv = ov; bi = oi; }
        }
        if (lane == 0) { rv[w] = bv; ri[w] = bi; }
        __syncthreads();
        if (w == 0) {
            bv = (lane < 8) ? rv[lane] : -INFINITY;
            bi = (lane < 8) ? ri[lane] : 0x7FFFFFFF;
            #pragma unroll
            for (int off = 4; off > 0; off >>= 1) {
                float ov = __shfl_down(bv, off);
                int   oi = __shfl_down(bi, off);
                if (ov > bv || (ov == bv && oi < bi)) { bv = ov; bi = oi; }
            }
            if (lane == 0) {
                pval[p] = bv;
                pidx[p] = bi;
                int pi = bi / 1681;
                int rr = bi - pi * 1681;
                int pj = rr / 41;
                pki[p] = pi; pkj[p] = pj; pkk[p] = rr - pj * 41;
                nlist = 0;
            }
        }
        __syncthreads();

        if (p < 3 && pval[p] > VTH) {
            if (tid < 49) {
                int di = tid / 7 - 3, dj = tid % 7 - 3;
                int ii = pki[p] + di, jj = pkj[p] + dj;
                if (ii >= 0 && ii <= 40 && jj >= 0 && jj <= 40) {
                    int k0 = pkk[p] - 3; if (k0 < 0)  k0 = 0;
                    int k1 = pkk[p] + 3; if (k1 > 40) k1 = 40;
                    int b0  = ii * 1681 + jj * 41 + k0;
                    int cnt = k1 - k0 + 1;
                    unsigned long long m = ((1ull << cnt) - 1ull) << (b0 & 31);
                    int w0 = b0 >> 5;
                    atomicAnd(&smask[w0], ~(unsigned int)m);
                    unsigned int hi = (unsigned int)(m >> 32);
                    if (hi) atomicAnd(&smask[w0 + 1], ~hi);
                    int s0 = (b0 > h) ? (b0 - h) >> 8 : 0;
                    int s1 = (b0 + cnt - 1 > h) ? (b0 + cnt - 1 - h) >> 8 : 0;
                    if (atomicMax(&flag[s0], p + 1) < p + 1) {
                        int q = atomicAdd(&nlist, 1); list[q] = s0;
                    }
                    if (s1 != s0 && atomicMax(&flag[s1], p + 1) < p + 1) {
                        int q = atomicAdd(&nlist, 1); list[q] = s1;
                    }
                }
            }
            __syncthreads();
            const int cnt = nlist;
            for (int base = 0; base < cnt; base += 64) {
                const int slot = base + w * 8 + s8;
                if (slot < cnt) {
                    const int s = list[slot];
                    const int ebase = h + 256 * s + 4 * l8;
                    float bv2; int bi2;
                    seg_scan8_core(dens, smask + 8 * s, ebase, h + 4 * l8, eclamp, bv2, bi2);
                    if (l8 == 0) { sval[s] = bv2; sidx[s] = bi2; }
                }
            }
        }
        __syncthreads();
    }

    if (tid < 4) {
        const int k   = tid;
        const float val = pval[k];
        const int   idx = pidx[k];
        const bool valid = val > VTH;
        float gx = 0.0f, gy = 0.0f, gz = 0.0f;
        if (valid) {
            gx = gxyz[idx * 3 + 0];
            gy = gxyz[idx * 3 + 1];
            gz = gxyz[idx * 3 + 2];
        }
        const float nm = nmask[n];
        const float* R = Rm + n * 9;
        const float* t = tp + n * 3;
        float wx = R[0] * gx + R[1] * gy + R[2] * gz + t[0];
        float wy = R[3] * gx + R[4] * gy + R[5] * gz + t[1];
        float wz = R[6] * gx + R[7] * gy + R[8] * gz + t[2];

        const size_t o3 = ((size_t)nc * 4 + k) * 3;
        out[o3 + 0] = gx * nm;
        out[o3 + 1] = gy * nm;
        out[o3 + 2] = gz * nm;
        out[6144 + o3 + 0] = wx * nm;
        out[6144 + o3 + 1] = wy * nm;
        out[6144 + o3 + 2] = wz * nm;
        const size_t o1 = (size_t)nc * 4 + k;
        out[12288 + o1] = (valid ? val : NEGV) * nm;
        out[14336 + o1] = (valid && nm != 0.0f) ? 1.0f : 0.0f;
    }
}

extern "C" void kernel_launch(void* const* d_in, const int* in_sizes, int n_in,
                              void* d_out, int out_size, void* d_ws, size_t ws_size,
                              hipStream_t stream) {
    const float* density  = (const float*)d_in[0];  // [1,128,4,G] f32
    const float* grid_xyz = (const float*)d_in[1];  // [G,3] f32
    const float* Rm    = (const float*)d_in[4];     // [1,128,3,3] f32
    const float* tpos  = (const float*)d_in[5];     // [1,128,3] f32
    const float* nmask = (const float*)d_in[6];     // [1,128] f32
    float* out = (float*)d_out;                     // 16384 f32

    unsigned int* mask = (unsigned int*)d_ws;       // 8704 B at ws+0

    build_mask<<<dim3(272), dim3(256), 0, stream>>>(grid_xyz, mask);

    if (ws_size >= (size_t)WS_NEEDED) {
        float* wval = (float*)((char*)d_ws + WS_TAB_OFF);
        int*   widx = (int*)((char*)d_ws + WS_TAB_OFF + 512 * NSEG * 4);
        scan_table<<<dim3(2048), dim3(256), 0, stream>>>(density, mask, wval, widx);
        nms_peaks<<<dim3(512), dim3(512), 0, stream>>>(density, grid_xyz, mask,
                                                       wval, widx, Rm, tpos, nmask, out);
    } else {
        fused_peaks<<<dim3(512), dim3(512), 0, stream>>>(density, grid_xyz, mask,
                                                         Rm, tpos, nmask, out);
    }
}

// Round 6
// 221.918 us; speedup vs baseline: 1.0441x; 1.0441x over previous
//
#include <hip/hip_runtime.h>

#define G_VOX  68921      // 41^3
#define GMAX   68920      // last valid element index
#define NSEG   272        // 272 segments of 256 elements (phase-shifted); last few are padding
#define MWORDS 2176       // 32-bit sphere-mask words (69632 bits)
#define NEGV (-1.0e9f)
#define VTH  (-1.0e8f)

__device__ __forceinline__ bool sphere_bit(const float* __restrict__ gxyz, int e) {
    if (e >= G_VOX) return false;
    float gx = gxyz[e * 3 + 0];
    float gy = gxyz[e * 3 + 1];
    float gz = gxyz[e * 3 + 2];
    float s  = __fadd_rn(__fadd_rn(__fmul_rn(gx, gx), __fmul_rn(gy, gy)),
                         __fmul_rn(gz, gz));
    return (__fsqrt_rn(s) <= 6.0f);   // bit-matches np.linalg.norm(grid_xyz) <= 6
}

// ---------------- Kernel 0: sphere word-mask ----------------
__global__ __launch_bounds__(256) void build_mask(
    const float* __restrict__ gxyz, unsigned int* __restrict__ mask)
{
    int idx = blockIdx.x * 256 + threadIdx.x;    // 0..69631
    unsigned long long bal = __ballot(sphere_bit(gxyz, idx));
    int lane = threadIdx.x & 63;
    if (lane == 0)       mask[idx >> 5] = (unsigned int)bal;
    else if (lane == 32) mask[idx >> 5] = (unsigned int)(bal >> 32);
}

// 8-lane segment scan core: lanes l8=0..7 cooperatively scan one 256-element segment.
// smw points at the mask word for this segment's first quad (global word 8*s).
// Loads are per-lane PREDICATED on a nonzero mask nibble (skips ~30% of HBM lines;
// empty bits cluster) but remain 8 independent iterations with uses deferred to the
// second loop -> VMEM latency still pipelined (this was R3's gain; R0 chained them).
// Two-word 64-bit mask extract (field straddles a word when sh>28 — the R1 bug).
// 3-level xor-shuffle reduce; all 8 lanes return the group winner.
__device__ __forceinline__ void seg_scan8_core(
    const float* __restrict__ dens, const unsigned int* smw,
    int ebase, int sh, int eclamp, float& bv, int& bi)
{
    bv = NEGV; bi = ebase;
    float4       dq[8];
    unsigned int bq[8];
    unsigned int wprev = smw[0];
    #pragma unroll
    for (int q = 0; q < 8; ++q) {
        const int e = ebase + 32 * q;
        const unsigned int wnext = smw[q + 1];
        unsigned long long mw = ((unsigned long long)wnext << 32) | wprev;
        bq[q] = (unsigned int)(mw >> sh) & 0xFu;
        wprev = wnext;
        const int ec = (e + 3 <= GMAX) ? e : eclamp;       // branchless tail clamp
        if (bq[q]) dq[q] = *reinterpret_cast<const float4*>(dens + ec);
    }
    #pragma unroll
    for (int q = 0; q < 8; ++q) {
        if (bq[q]) {
            const int e = ebase + 32 * q;
            float v0 = (bq[q] & 1u) ? dq[q].x : NEGV;
            float v1 = (bq[q] & 2u) ? dq[q].y : NEGV;
            float v2 = (bq[q] & 4u) ? dq[q].z : NEGV;
            float v3 = (bq[q] & 8u) ? dq[q].w : NEGV;
            if (v0 > bv) { bv = v0; bi = e;     }   // ascending e + strict > = first occurrence
            if (v1 > bv) { bv = v1; bi = e + 1; }
            if (v2 > bv) { bv = v2; bi = e + 2; }
            if (v3 > bv) { bv = v3; bi = e + 3; }
        }
    }
    #pragma unroll
    for (int off = 4; off > 0; off >>= 1) {     // 3-level reduce within 8-lane group
        float ov = __shfl_xor(bv, off);
        int   oi = __shfl_xor(bi, off);
        if (ov > bv || (ov == bv && oi < bi)) { bv = ov; bi = oi; }
    }
}

// ---------------- Fused kernel: one density pass + K=4 pick/NMS, one block per nc ----------------
__global__ __launch_bounds__(512) void fused_peaks(
    const float* __restrict__ density,
    const float* __restrict__ gxyz,
    const unsigned int* __restrict__ maskg,
    const float* __restrict__ Rm, const float* __restrict__ tp,
    const float* __restrict__ nmask,
    float* __restrict__ out)
{
    __shared__ unsigned int smask[MWORDS + 2];   // +2: suppression's 64-bit clears touch wd+1
    __shared__ float sval[NSEG];
    __shared__ int   sidx[NSEG];
    __shared__ int   flag[NSEG];
    __shared__ int   list[104];
    __shared__ int   nlist;
    __shared__ float rv[8];
    __shared__ int   ri[8];
    __shared__ float pval[4];
    __shared__ int   pidx[4];
    __shared__ int   pki[4], pkj[4], pkk[4];

    const int tid  = threadIdx.x;
    const int nc   = blockIdx.x;                 // 0..511
    const int n    = nc >> 2;
    const int h    = (-nc) & 3;                  // phase: nc*68921 + h == 0 (mod 4)
    const int lane = tid & 63;
    const int w    = tid >> 6;                   // wave 0..7
    const int s8   = lane >> 3;                  // local segment in group 0..7
    const int l8   = lane & 7;                   // lane-in-segment 0..7
    const float* dens = density + (size_t)nc * G_VOX;
    const int eclamp = h + ((GMAX - 3 - h) & ~3);  // last aligned in-bounds quad start

    for (int i = tid; i < MWORDS + 2; i += 512) smask[i] = (i < MWORDS) ? maskg[i] : 0u;
    for (int i = tid; i < NSEG; i += 512) flag[i] = 0;
    __syncthreads();

    // ---- single density pass: wave w scans segment groups g = w, w+8, ... ----
    for (int g = w; g < 34; g += 8) {
        const int s = g * 8 + s8;                // 0..271, each exactly once
        const int ebase = h + 256 * s + 4 * l8;
        float bv; int bi;
        seg_scan8_core(dens, smask + 8 * s, ebase, h + 4 * l8, eclamp, bv, bi);
        if (l8 == 0) { sval[s] = bv; sidx[s] = bi; }
    }
    __syncthreads();

    // ---- K=4 rounds: table argmax + LDS-mask suppression + segment recompute ----
    for (int p = 0; p < 4; ++p) {
        float bv = -INFINITY;
        int   bi = 0x7FFFFFFF;
        if (tid < NSEG) { bv = sval[tid]; bi = sidx[tid]; }
        #pragma unroll
        for (int off = 32; off > 0; off >>= 1) {
            float ov = __shfl_down(bv, off);
            int   oi = __shfl_down(bi, off);
            if (ov > bv || (ov == bv && oi < bi)) { bv = ov; bi = oi; }
        }
        if (lane == 0) { rv[w] = bv; ri[w] = bi; }
        __syncthreads();
        if (w == 0) {
            bv = (lane < 8) ? rv[lane] : -INFINITY;
            bi = (lane < 8) ? ri[lane] : 0x7FFFFFFF;
            #pragma unroll
            for (int off = 4; off > 0; off >>= 1) {
                float ov = __shfl_down(bv, off);
                int   oi = __shfl_down(bi, off);
                if (ov > bv || (ov == bv && oi < bi)) { bv = ov; bi = oi; }
            }
            if (lane == 0) {
                pval[p] = bv;
                pidx[p] = bi;
                int pi = bi / 1681;
                int rr = bi - pi * 1681;
                int pj = rr / 41;
                pki[p] = pi; pkj[p] = pj; pkk[p] = rr - pj * 41;
                nlist = 0;
            }
        }
        __syncthreads();

        if (p < 3 && pval[p] > VTH) {
            // clear 7x7x7 Chebyshev cube bits in LDS mask; collect segments needing
            // recompute. A segment is stale ONLY if its stored winner lies inside the
            // cube (bits outside the cube are untouched, so its max is otherwise
            // unchanged). Every cube-overlapping segment is examined by >=1 column,
            // and the winner-in-cube condition is column-independent -> safe.
            if (tid < 49) {
                int di = tid / 7 - 3, dj = tid % 7 - 3;
                int ii = pki[p] + di, jj = pkj[p] + dj;
                if (ii >= 0 && ii <= 40 && jj >= 0 && jj <= 40) {
                    int k0 = pkk[p] - 3; if (k0 < 0)  k0 = 0;
                    int k1 = pkk[p] + 3; if (k1 > 40) k1 = 40;
                    int b0  = ii * 1681 + jj * 41 + k0;
                    int cnt = k1 - k0 + 1;
                    unsigned long long m = ((1ull << cnt) - 1ull) << (b0 & 31);
                    int w0 = b0 >> 5;
                    atomicAnd(&smask[w0], ~(unsigned int)m);
                    unsigned int hi = (unsigned int)(m >> 32);
                    if (hi) atomicAnd(&smask[w0 + 1], ~hi);
                    // phase-shifted segment ids containing this run
                    int s0 = (b0 > h) ? (b0 - h) >> 8 : 0;
                    int s1 = (b0 + cnt - 1 > h) ? (b0 + cnt - 1 - h) >> 8 : 0;
                    #pragma unroll
                    for (int t2 = 0; t2 < 2; ++t2) {
                        const int s = t2 ? s1 : s0;
                        if (t2 && s1 == s0) break;
                        // winner-in-cube test for segment s
                        int widx = sidx[s];
                        int wi = widx / 1681;
                        int wr = widx - wi * 1681;
                        int wj = wr / 41;
                        int wk = wr - wj * 41;
                        int ci = wi - pki[p]; if (ci < 0) ci = -ci;
                        int cj = wj - pkj[p]; if (cj < 0) cj = -cj;
                        int ck = wk - pkk[p]; if (ck < 0) ck = -ck;
                        if (ci <= 3 && cj <= 3 && ck <= 3) {
                            if (atomicMax(&flag[s], p + 1) < p + 1) {
                                int q = atomicAdd(&nlist, 1); list[q] = s;
                            }
                        }
                    }
                }
            }
            __syncthreads();
            // recompute flagged segments: one 8-lane group per list entry (64 segs/sweep)
            const int cnt = nlist;
            for (int base = 0; base < cnt; base += 64) {
                const int slot = base + w * 8 + s8;
                if (slot < cnt) {                // uniform within the 8-lane group
                    const int s = list[slot];
                    const int ebase = h + 256 * s + 4 * l8;
                    float bv2; int bi2;
                    seg_scan8_core(dens, smask + 8 * s, ebase, h + 4 * l8, eclamp, bv2, bi2);
                    if (l8 == 0) { sval[s] = bv2; sidx[s] = bi2; }
                }
            }
        }
        __syncthreads();
    }

    // ---- epilogue: one peak per thread ----
    if (tid < 4) {
        const int k   = tid;
        const float val = pval[k];
        const int   idx = pidx[k];
        const bool valid = val > VTH;
        float gx = 0.0f, gy = 0.0f, gz = 0.0f;
        if (valid) {
            gx = gxyz[idx * 3 + 0];
            gy = gxyz[idx * 3 + 1];
            gz = gxyz[idx * 3 + 2];
        }
        const float nm = nmask[n];
        const float* R = Rm + n * 9;
        const float* t = tp + n * 3;
        float wx = R[0] * gx + R[1] * gy + R[2] * gz + t[0];
        float wy = R[3] * gx + R[4] * gy + R[5] * gz + t[1];
        float wz = R[6] * gx + R[7] * gy + R[8] * gz + t[2];

        const size_t o3 = ((size_t)nc * 4 + k) * 3;
        out[o3 + 0] = gx * nm;                       // coords_local [1,128,4,4,3]
        out[o3 + 1] = gy * nm;
        out[o3 + 2] = gz * nm;
        out[6144 + o3 + 0] = wx * nm;                // coords_global
        out[6144 + o3 + 1] = wy * nm;
        out[6144 + o3 + 2] = wz * nm;
        const size_t o1 = (size_t)nc * 4 + k;
        out[12288 + o1] = (valid ? val : NEGV) * nm; // scores
        out[14336 + o1] = (valid && nm != 0.0f) ? 1.0f : 0.0f;  // mask
    }
}

extern "C" void kernel_launch(void* const* d_in, const int* in_sizes, int n_in,
                              void* d_out, int out_size, void* d_ws, size_t ws_size,
                              hipStream_t stream) {
    const float* density  = (const float*)d_in[0];  // [1,128,4,G] f32
    const float* grid_xyz = (const float*)d_in[1];  // [G,3] f32
    const float* Rm    = (const float*)d_in[4];     // [1,128,3,3] f32
    const float* tpos  = (const float*)d_in[5];     // [1,128,3] f32
    const float* nmask = (const float*)d_in[6];     // [1,128] f32
    float* out = (float*)d_out;                     // 16384 f32

    unsigned int* mask = (unsigned int*)d_ws;       // 8704 B

    build_mask<<<dim3(272), dim3(256), 0, stream>>>(grid_xyz, mask);
    fused_peaks<<<dim3(512), dim3(512), 0, stream>>>(density, grid_xyz, mask,
                                                     Rm, tpos, nmask, out);
}